// Round 3
// baseline (40.906 us; speedup 1.0000x reference)
//
#include <hip/hip_runtime.h>
#include <hip/hip_bf16.h>
#include <stdint.h>

#define H_EDGES 4096
#define N_NODES 20000
#define FIN 256
#define FOUT 128
#define DEG 32
#define ROWS_TOTAL (H_EDGES + N_NODES)  // 24096 = 753 * 32

typedef float f32x4 __attribute__((ext_vector_type(4)));
typedef short s16x8 __attribute__((ext_vector_type(8)));
typedef unsigned short u16;

__device__ __forceinline__ u16 f2bf(float f) {
    unsigned u = __builtin_bit_cast(unsigned, f);
    return (u16)((u + 0x7FFFu + ((u >> 16) & 1u)) >> 16);   // RNE
}
__device__ __forceinline__ float bf2f(u16 h) {
    unsigned u = ((unsigned)h) << 16;
    return __builtin_bit_cast(float, u);
}

// ---------- k0: Wq fp32 [256][128] -> bt bf16 [col][k] (linear) -------------
__global__ __launch_bounds__(256)
void k0_prep(const float* __restrict__ Wq, u16* __restrict__ bt) {
    const int s = blockIdx.x * 256 + threadIdx.x;   // 0..4095
    const int c = s >> 5, kslot = s & 31;
    const int k0 = kslot * 8;
    s16x8 v;
    #pragma unroll
    for (int j = 0; j < 8; ++j) v[j] = (short)f2bf(Wq[(size_t)(k0 + j) * FOUT + c]);
    *(s16x8*)(bt + (size_t)(c * FIN + k0)) = v;
}

// ---------- k1: [hedge;node] @ Wq via bf16 MFMA, no LDS, 3012 waves ---------
// Block = 256 thr = 4 waves over a 32-row x 128-col tile:
//   wave w: rows rb + (w&1)*16, cols (w>>1)*64  (A rows shared by 2 waves -> L1)
// B-fragments read from global (64KB, L1/L2-resident). q stored fp32, k bf16.
__global__ __launch_bounds__(256)
void k1_gemm(const float* __restrict__ hedge, const float* __restrict__ node,
             const u16* __restrict__ bt, float* __restrict__ qf,
             u16* __restrict__ kb) {
    const int t = threadIdx.x;
    const int w = t >> 6, l = t & 63;
    const int lr = l & 15, lp = l >> 4;
    const long rb = (long)blockIdx.x * 32 + (w & 1) * 16;
    const int c0 = (w >> 1) * 64;
    const long row = rb + lr;
    const float* pa = row < H_EDGES ? hedge + row * FIN
                                    : node + (row - H_EDGES) * FIN;

    f32x4 acc[4];
    #pragma unroll
    for (int j = 0; j < 4; ++j) acc[j] = (f32x4){0.f, 0.f, 0.f, 0.f};

    #pragma unroll
    for (int ks = 0; ks < 8; ++ks) {
        const int koff = ks * 32 + lp * 8;
        f32x4 u = *(const f32x4*)(pa + koff);
        f32x4 v = *(const f32x4*)(pa + koff + 4);
        s16x8 a;
        #pragma unroll
        for (int j = 0; j < 4; ++j) { a[j] = (short)f2bf(u[j]); a[j+4] = (short)f2bf(v[j]); }
        #pragma unroll
        for (int cf = 0; cf < 4; ++cf) {
            const int col = c0 + cf * 16 + lr;
            s16x8 b = *(const s16x8*)(bt + (size_t)col * FIN + koff);
            acc[cf] = __builtin_amdgcn_mfma_f32_16x16x32_bf16(a, b, acc[cf], 0, 0, 0);
        }
    }

    // D map: row = lp*4+i, col = lr within frag. rb<H_EDGES is block-uniform.
    if (rb < H_EDGES) {
        #pragma unroll
        for (int i = 0; i < 4; ++i) {
            const long ro = rb + lp * 4 + i;
            #pragma unroll
            for (int cf = 0; cf < 4; ++cf)
                qf[(size_t)ro * FOUT + c0 + cf * 16 + lr] = acc[cf][i];
        }
    } else {
        #pragma unroll
        for (int i = 0; i < 4; ++i) {
            const long ro = rb - H_EDGES + lp * 4 + i;
            #pragma unroll
            for (int cf = 0; cf < 4; ++cf)
                kb[(size_t)ro * FOUT + c0 + cf * 16 + lr] = f2bf(acc[cf][i]);
        }
    }
}

// ---------- k2: one 64-lane wave per hyperedge ------------------------------
__global__ __launch_bounds__(64)
void k2_attn(const float* __restrict__ qf, const u16* __restrict__ kb,
             const int* __restrict__ col_idx, float* __restrict__ out_t) {
    const int h = blockIdx.x, l = threadIdx.x;
    __shared__ u16  k_l[DEG][136];   // 272B stride: 16B-aligned, bank-spread
    __shared__ float q_l[FOUT];
    __shared__ float w_l[DEG];
    __shared__ int   c_l[DEG];

    if (l < DEG) c_l[l] = col_idx[(size_t)h * DEG + l];
    q_l[l]      = qf[(size_t)h * FOUT + l];
    q_l[l + 64] = qf[(size_t)h * FOUT + 64 + l];
    __syncthreads();

    // gather 32 rows x 256B bf16 (512 x 16B slots, 8 per lane)
    #pragma unroll
    for (int it = 0; it < 8; ++it) {
        const int s = l + 64 * it;
        const int m = s >> 4, sl = s & 15;
        *(s16x8*)&k_l[m][sl * 8] =
            *(const s16x8*)(kb + (size_t)c_l[m] * FOUT + sl * 8);
    }
    __syncthreads();

    // scores: 2 lanes per member, 64 elems each
    const int m = l >> 1, half = l & 1;
    float p = 0.f;
    #pragma unroll
    for (int j = 0; j < 8; ++j) {
        s16x8 kv = *(const s16x8*)&k_l[m][half * 64 + j * 8];
        #pragma unroll
        for (int e = 0; e < 8; ++e)
            p = fmaf(q_l[half * 64 + j * 8 + e], bf2f((u16)kv[e]), p);
    }
    p += __shfl_xor(p, 1);
    float sc = p * 0.08838834764831845f;   // 1/sqrt(128)

    // dedup (both lanes of a pair compute identically)
    const int cm = c_l[m];
    bool valid = true;
    for (int j = 0; j < m; ++j)
        if (c_l[j] == cm) valid = false;
    float sv = valid ? sc : -INFINITY;
    float mx = sv;
    #pragma unroll
    for (int d = 1; d < 64; d <<= 1) mx = fmaxf(mx, __shfl_xor(mx, d));
    float e = valid ? expf(sv - mx) : 0.f;
    float sum = e;
    #pragma unroll
    for (int d = 1; d < 64; d <<= 1) sum += __shfl_xor(sum, d);
    if (half == 0) w_l[m] = e * 2.f / sum;  // 64-lane sum double-counts pairs
    __syncthreads();

    // aggregate: lane l -> features l and l+64 (coalesced fp32 store)
    float acc0 = 0.f, acc1 = 0.f;
    #pragma unroll
    for (int mm = 0; mm < DEG; ++mm) {
        const float wv = w_l[mm];
        acc0 = fmaf(wv, bf2f(k_l[mm][l]), acc0);
        acc1 = fmaf(wv, bf2f(k_l[mm][l + 64]), acc1);
    }
    out_t[(size_t)h * FOUT + l]      = acc0;
    out_t[(size_t)h * FOUT + l + 64] = acc1;
}

// ---------- k3: transpose [H][FOUT] fp32 -> [FOUT][H] -----------------------
__global__ __launch_bounds__(256)
void k3_transpose(const float* __restrict__ out_t, float* __restrict__ out) {
    __shared__ float tile[32][33];
    const int tx = threadIdx.x;   // 0..31
    const int ty = threadIdx.y;   // 0..7
    const int h0 = blockIdx.x * 32;
    const int f0 = blockIdx.y * 32;
    #pragma unroll
    for (int j = 0; j < 4; ++j) {
        const int h = h0 + ty + j * 8;
        tile[ty + j * 8][tx] = out_t[(size_t)h * FOUT + f0 + tx];
    }
    __syncthreads();
    #pragma unroll
    for (int j = 0; j < 4; ++j) {
        const int f = f0 + ty + j * 8;
        out[(size_t)f * H_EDGES + h0 + tx] = tile[tx][ty + j * 8];
    }
}

extern "C" void kernel_launch(void* const* d_in, const int* in_sizes, int n_in,
                              void* d_out, int out_size, void* d_ws, size_t ws_size,
                              hipStream_t stream) {
    const float* hedge = (const float*)d_in[0];
    const float* node  = (const float*)d_in[1];
    const float* Wq    = (const float*)d_in[2];
    const int* col_idx = (const int*)d_in[4];   // row_idx (d_in[3]) == e/DEG by construction
    float* out = (float*)d_out;

    char* ws = (char*)d_ws;
    float* qf    = (float*)ws;                                   // 4096*128 fp32  = 2 MB
    u16*   kb    = (u16*)(ws + (size_t)H_EDGES * FOUT * 4);      // 20000*128 bf16 = 5.12 MB
    float* out_t = (float*)(ws + (size_t)H_EDGES * FOUT * 4
                               + (size_t)N_NODES * FOUT * 2);    // 4096*128 fp32  = 2 MB
    u16*   bt    = (u16*)(ws + (size_t)H_EDGES * FOUT * 4
                             + (size_t)N_NODES * FOUT * 2
                             + (size_t)H_EDGES * FOUT * 4);      // 128*256 bf16 = 64 KB

    k0_prep<<<16, 256, 0, stream>>>(Wq, bt);
    k1_gemm<<<ROWS_TOTAL / 32, 256, 0, stream>>>(hedge, node, bt, qf, kb);
    k2_attn<<<H_EDGES, 64, 0, stream>>>(qf, kb, col_idx, out_t);
    k3_transpose<<<dim3(H_EDGES / 32, FOUT / 32), dim3(32, 8), 0, stream>>>(out_t, out);
}

// Round 5
// 35.999 us; speedup vs baseline: 1.1363x; 1.1363x over previous
//
#include <hip/hip_runtime.h>
#include <hip/hip_bf16.h>
#include <stdint.h>

#define H_EDGES 4096
#define N_NODES 20000
#define FIN 256
#define FOUT 128
#define DEG 32
#define ROWS_TOTAL 24096      // 4096 + 20000
#define G1_BLOCKS 377         // ceil(24096 / 64)

typedef float f32x4 __attribute__((ext_vector_type(4)));
typedef short s16x8 __attribute__((ext_vector_type(8)));
typedef unsigned short u16;

__device__ __forceinline__ u16 f2bf(float f) {
    return __builtin_bit_cast(u16, __float2bfloat16(f));   // RNE
}
__device__ __forceinline__ float bf2f(u16 h) {
    unsigned u = ((unsigned)h) << 16;
    return __builtin_bit_cast(float, u);
}

// ---------- g1: [hedge;node] @ Wq via bf16 MFMA ----------------------------
// 377 blocks x 256 thr (4 waves). Block = 64 rows x ALL 128 cols.
// Full B (256x128 bf16 = 64KB) built in LDS per block from Wq (transposed,
// XOR-swizzled slots). Wave = 16 rows x 128 cols = 8 col-frags x 8 k-steps.
// A: 16 upfront 16B HBM loads per lane (deep in-flight queue).
__global__ __launch_bounds__(256)
void g1_gemm(const float* __restrict__ hedge, const float* __restrict__ node,
             const float* __restrict__ Wq, float* __restrict__ qf,
             u16* __restrict__ kb) {
    __shared__ u16 blds[FOUT * FIN];   // [col][32 slot ^ (col&7)][8] = 64 KB
    const int t = threadIdx.x;
    const int w = t >> 6, l = t & 63;
    const int lr = l & 15, lp = l >> 4;
    const long rb  = (long)blockIdx.x * 64 + w * 16;
    const long row = rb + lr;
    const long arow = row < ROWS_TOTAL ? row : ROWS_TOTAL - 1;  // clamp; OOB never stored
    const float* pa = arow < H_EDGES ? hedge + arow * FIN
                                     : node + (arow - H_EDGES) * FIN;

    // A: issue all 16 global loads up-front
    f32x4 au[8], av[8];
    #pragma unroll
    for (int ks = 0; ks < 8; ++ks) {
        au[ks] = *(const f32x4*)(pa + ks * 32 + lp * 8);
        av[ks] = *(const f32x4*)(pa + ks * 32 + lp * 8 + 4);
    }

    // B build: thread t -> col = t>>1, slots (t&1)*16 .. +15 (k = slot*8..+7)
    {
        const int col   = t >> 1;
        const int sbase = (t & 1) * 16;
        #pragma unroll
        for (int j = 0; j < 16; ++j) {
            const int s  = sbase + j;
            const int k0 = s * 8;
            s16x8 b;
            #pragma unroll
            for (int e = 0; e < 8; ++e)
                b[e] = (short)f2bf(Wq[(size_t)(k0 + e) * FOUT + col]);
            *(s16x8*)(blds + (size_t)(col * 32 + (s ^ (col & 7))) * 8) = b;
        }
    }
    __syncthreads();

    f32x4 acc[8];
    #pragma unroll
    for (int j = 0; j < 8; ++j) acc[j] = (f32x4){0.f, 0.f, 0.f, 0.f};

    #pragma unroll
    for (int ks = 0; ks < 8; ++ks) {
        s16x8 a;
        #pragma unroll
        for (int j = 0; j < 4; ++j) {
            a[j]     = (short)f2bf(au[ks][j]);
            a[j + 4] = (short)f2bf(av[ks][j]);
        }
        #pragma unroll
        for (int cf = 0; cf < 8; ++cf) {
            const int col = cf * 16 + lr;
            s16x8 b = *(const s16x8*)(blds +
                (size_t)(col * 32 + ((ks * 4 + lp) ^ (col & 7))) * 8);
            acc[cf] = __builtin_amdgcn_mfma_f32_16x16x32_bf16(a, b, acc[cf], 0, 0, 0);
        }
    }

    // D map: row = lp*4+i, col = lr. rb<H_EDGES is block-uniform (bid<64).
    if (rb < H_EDGES) {
        #pragma unroll
        for (int i = 0; i < 4; ++i) {
            const long gr = rb + lp * 4 + i;
            #pragma unroll
            for (int cf = 0; cf < 8; ++cf)
                qf[gr * FOUT + cf * 16 + lr] = acc[cf][i];
        }
    } else {
        #pragma unroll
        for (int i = 0; i < 4; ++i) {
            const long gr = rb + lp * 4 + i;
            if (gr < ROWS_TOTAL) {
                #pragma unroll
                for (int cf = 0; cf < 8; ++cf)
                    kb[(gr - H_EDGES) * FOUT + cf * 16 + lr] = f2bf(acc[cf][i]);
            }
        }
    }
}

// ---------- g2: per-edge attention + fused transposed store ----------------
// 1024 blocks x 256 thr = 4 edges/block, one 64-lane wave per edge.
// Ends with an LDS micro-transpose: block writes out[f][e0..e0+3] as float4.
__global__ __launch_bounds__(256)
void g2_attn(const float* __restrict__ qf, const u16* __restrict__ kb,
             const int* __restrict__ col_idx, float* __restrict__ out) {
    __shared__ __align__(16) char smem[37888];
    const int t = threadIdx.x;
    const int w = t >> 6, l = t & 63;
    const int e = blockIdx.x * 4 + w;

    char* base = smem + w * 9472;                 // per-wave slice
    u16 (*k_l)[136] = (u16(*)[136])base;          // 32 x 136 u16 = 8704 B
    float* q_l = (float*)(base + 8704);           // 128 f32
    float* w_l = q_l + 128;                       // 32 f32
    int*   c_l = (int*)(w_l + 32);                // 32 int

    if (l < DEG) c_l[l] = col_idx[(size_t)e * DEG + l];
    q_l[l]      = qf[(size_t)e * FOUT + l];
    q_l[l + 64] = qf[(size_t)e * FOUT + 64 + l];
    __syncthreads();

    #pragma unroll
    for (int it = 0; it < 8; ++it) {              // gather 32 rows x 256 B
        const int s = l + 64 * it;
        const int m = s >> 4, sl = s & 15;
        *(s16x8*)&k_l[m][sl * 8] =
            *(const s16x8*)(kb + (size_t)c_l[m] * FOUT + sl * 8);
    }
    __syncthreads();

    // scores: 2 lanes per member, 64 elems each
    const int m = l >> 1, he = l & 1;
    float p = 0.f;
    #pragma unroll
    for (int j = 0; j < 8; ++j) {
        s16x8 kv = *(const s16x8*)&k_l[m][he * 64 + j * 8];
        #pragma unroll
        for (int ee = 0; ee < 8; ++ee)
            p = fmaf(q_l[he * 64 + j * 8 + ee], bf2f((u16)kv[ee]), p);
    }
    p += __shfl_xor(p, 1);
    const float sc = p * 0.08838834764831845f;    // 1/sqrt(128)

    // dedup (first occurrence only) + softmax; pair lanes duplicate
    const int cm = c_l[m];
    bool valid = true;
    for (int j = 0; j < m; ++j)
        if (c_l[j] == cm) valid = false;
    const float sv = valid ? sc : -INFINITY;
    float mx = sv;
    #pragma unroll
    for (int d = 1; d < 64; d <<= 1) mx = fmaxf(mx, __shfl_xor(mx, d));
    const float ex = valid ? __expf(sv - mx) : 0.f;
    float sum = ex;
    #pragma unroll
    for (int d = 1; d < 64; d <<= 1) sum += __shfl_xor(sum, d);
    if (he == 0) w_l[m] = ex * 2.f / sum;         // 64-lane sum double-counts pairs
    __syncthreads();

    float a0 = 0.f, a1 = 0.f;
    #pragma unroll
    for (int mm = 0; mm < DEG; ++mm) {
        const float wv = w_l[mm];
        a0 = fmaf(wv, bf2f(k_l[mm][l]), a0);
        a1 = fmaf(wv, bf2f(k_l[mm][l + 64]), a1);
    }
    __syncthreads();                              // all waves done with k_l

    // micro-transpose: tile[f][edge-in-block], then float4 rows to out
    float (*tile)[4] = (float(*)[4])smem;
    tile[l][w]      = a0;
    tile[l + 64][w] = a1;
    __syncthreads();
    if (t < FOUT) {
        f32x4 v = *(const f32x4*)tile[t];
        *(f32x4*)(out + (size_t)t * H_EDGES + blockIdx.x * 4) = v;
    }
}

extern "C" void kernel_launch(void* const* d_in, const int* in_sizes, int n_in,
                              void* d_out, int out_size, void* d_ws, size_t ws_size,
                              hipStream_t stream) {
    const float* hedge   = (const float*)d_in[0];
    const float* node    = (const float*)d_in[1];
    const float* Wq      = (const float*)d_in[2];
    const int*   col_idx = (const int*)d_in[4];   // row_idx (d_in[3]) == e/DEG by construction
    float* out = (float*)d_out;

    char* ws = (char*)d_ws;
    float* qf = (float*)ws;                                  // 4096*128 f32  = 2 MB
    u16*   kb = (u16*)(ws + (size_t)H_EDGES * FOUT * 4);     // 20000*128 bf16 = 5.12 MB

    g1_gemm<<<G1_BLOCKS, 256, 0, stream>>>(hedge, node, Wq, qf, kb);
    g2_attn<<<H_EDGES / 4, 256, 0, stream>>>(qf, kb, col_idx, out);
}